// Round 4
// baseline (457.039 us; speedup 1.0000x reference)
//
#include <hip/hip_runtime.h>

// DeepSeek MoE (N=2048, D=768, I=3072, E=8, K=2 + shared expert), fp32 in/out,
// bf16 MFMA compute. R7: (a) all weight transposes use a 128x64 tile through a
// swizzled bf16 LDS scratch -- 256 B contiguous dest segments (vs 128 B),
// conflict-free-ish LDS on both phases; (b) GEMM2-shared (act[0:2048) @ w2sb,
// splitk=1) folded into K3 so it overlaps routed GEMM1 + w2 transposes instead
// of serializing behind them; K4 is routed-only splitk=2. Pipeline:
//   K1 prep_lite: cast_x + gating + shared-weight transposes
//   K2: shared GEMM1 + w1/w3 transposes + route_build
//   K3: routed GEMM1 + w2 transposes + GEMM2-shared
//   K4: GEMM2-routed (splitk=2)   K5: combine

#define D_ 768
#define I_ 3072
#define E_ 8
#define NTOK 2048
#define NPMAX 5120          // 4096 pairs + worst-case 128-padding per expert
#define MAXTILES 40
#define NSHT 16
#define ROWS (NTOK + NPMAX)
#define SPLITK 2
#define KS_ (I_ / SPLITK)   // 1536

typedef __bf16 bf16x8 __attribute__((ext_vector_type(8)));
typedef float floatx4 __attribute__((ext_vector_type(4)));

#define GLOAD_LDS16(g, l) __builtin_amdgcn_global_load_lds( \
    (const __attribute__((address_space(1))) void*)(g),     \
    (__attribute__((address_space(3))) void*)(l), 16, 0, 0)

__device__ __forceinline__ unsigned short f2b(float f) {
    unsigned int u = __float_as_uint(f);
    u += 0x7fffu + ((u >> 16) & 1u);          // RNE to bf16
    return (unsigned short)(u >> 16);
}

// ---- 128x64 fp32->bf16 transpose tile through swizzled bf16 LDS scratch ----
// src s[R][C] (leading dim C, R = src rows = dst leading dim), dst d[C][R].
// Tile: src rows r0..r0+127, cols c0..c0+63 -> dst rows c0..c0+63, 128 shorts
// contiguous at r0 (256 B dest segments). LDS (8192 shorts = 16 KB):
// logical (r,c) at phys r*64 + (c&3) + 4*(((c>>2)+(r>>3))&15) -- granule
// rotation keyed by r>>3 so phase-2's 16 rs-groups hit 16 distinct granules.
__device__ __forceinline__ void transpose_tile128(
    const float* __restrict__ s, unsigned short* __restrict__ d,
    int R, int C, int r0, int c0, unsigned short* t, int tid) {
#pragma unroll
    for (int j = 0; j < 8; j++) {
        int slot = tid + j * 256;          // 0..2047
        int rr = slot >> 4;                // 0..127
        int gr = slot & 15;                // granule (4 floats)
        float4 v = *(const float4*)(s + (size_t)(r0 + rr) * C + c0 + gr * 4);
        unsigned short o[4] __attribute__((aligned(8)));
        o[0] = f2b(v.x); o[1] = f2b(v.y); o[2] = f2b(v.z); o[3] = f2b(v.w);
        *(uint2*)(t + rr * 64 + 4 * ((gr + (rr >> 3)) & 15)) = *(const uint2*)o;
    }
    __syncthreads();
#pragma unroll
    for (int j = 0; j < 4; j++) {
        int slot = tid + j * 256;          // 0..1023
        int c = slot >> 4;                 // dst row 0..63
        int m = slot & 15;                 // rs-group: src rows m*8..m*8+7
        int base = (c & 3) + 4 * (((c >> 2) + m) & 15);
        unsigned short o[8] __attribute__((aligned(16)));
#pragma unroll
        for (int i = 0; i < 8; i++) o[i] = t[(m * 8 + i) * 64 + base];
        *(int4*)(d + (size_t)(c0 + c) * R + r0 + m * 8) = *(const int4*)o;
    }
}

// ---------------- K1: cast_x + gating + shared-weight transposes ------------

__global__ __launch_bounds__(256) void prep_lite_kernel(
    const float* __restrict__ x, const float* __restrict__ gw,
    const float* __restrict__ gbias,
    const float* __restrict__ w1s, const float* __restrict__ w3s,
    const float* __restrict__ w2s,
    unsigned short* __restrict__ xb,
    unsigned short* __restrict__ w1sb, unsigned short* __restrict__ w3sb,
    unsigned short* __restrict__ w2sb,
    int* __restrict__ idx, float* __restrict__ wts) {
    __shared__ unsigned short t[128 * 64];
    int b = blockIdx.x, tid = threadIdx.x;
    if (b < 864) {
        int z = b / 288, r = b % 288;
        if (z < 2) {            // w1s/w3s: [768][3072]
            int by = r / 48, bx = r % 48;
            transpose_tile128(z ? w3s : w1s, z ? w3sb : w1sb, D_, I_,
                              by * 128, bx * 64, t, tid);
        } else {                // w2s: [3072][768]
            int by = r / 12, bx = r % 12;
            transpose_tile128(w2s, w2sb, I_, D_, by * 128, bx * 64, t, tid);
        }
    } else if (b < 2400) {
        int gid = (b - 864) * 256 + tid;
        float4 v = *(const float4*)(x + (size_t)gid * 4);
        ushort4 o;
        o.x = f2b(v.x); o.y = f2b(v.y); o.z = f2b(v.z); o.w = f2b(v.w);
        *(ushort4*)(xb + (size_t)gid * 4) = o;
    } else {
        int tok = (b - 2400) * 4 + (tid >> 6);
        int lane = tid & 63;
        float z[E_];
#pragma unroll
        for (int e = 0; e < E_; e++) z[e] = 0.f;
        const float* xr = x + (size_t)tok * D_;
        for (int j = lane; j < D_; j += 64) {
            float xv = xr[j];
            const float* g = gw + (size_t)j * E_;
#pragma unroll
            for (int e = 0; e < E_; e++) z[e] += xv * g[e];
        }
#pragma unroll
        for (int off = 32; off > 0; off >>= 1)
#pragma unroll
            for (int e = 0; e < E_; e++) z[e] += __shfl_down(z[e], off, 64);
        if (lane == 0) {
            float s[E_], r[E_];
#pragma unroll
            for (int e = 0; e < E_; e++) {
                float zz = z[e];
                float sp = zz > 0.f ? zz + log1pf(expf(-zz)) : log1pf(expf(zz));
                s[e] = sqrtf(sp);
                r[e] = s[e] + gbias[e];
            }
            int i0 = 0;
            for (int e = 1; e < E_; e++) if (r[e] > r[i0]) i0 = e;
            int i1 = (i0 == 0) ? 1 : 0;
            for (int e = 0; e < E_; e++) if (e != i0 && r[e] > r[i1]) i1 = e;
            float w0 = s[i0], w1v = s[i1];
            float inv = 1.f / fmaxf(w0 + w1v, 1e-6f);
            idx[2 * tok] = i0; idx[2 * tok + 1] = i1;
            wts[2 * tok] = w0 * inv; wts[2 * tok + 1] = w1v * inv;
        }
    }
}

// ---------------- K2: shared GEMM1 + w1/w3 transposes + route_build ---------
// grid (48, 113). byi==0: route_build at bxi==0. t=byi-1 in [0,112):
// t%7==0 -> shared GEMM tile mt=t/7 (16); else transpose slot (96*48=4608).

__launch_bounds__(256)
__global__ void gemm_shared_kernel(const unsigned short* __restrict__ xb,
                                   const unsigned short* __restrict__ w1sb,
                                   const unsigned short* __restrict__ w3sb,
                                   unsigned short* __restrict__ act,
                                   const float* __restrict__ w1,
                                   const float* __restrict__ w3,
                                   unsigned short* __restrict__ w1b,
                                   unsigned short* __restrict__ w3b,
                                   const int* __restrict__ idx,
                                   const float* __restrict__ wts,
                                   int* __restrict__ pair_token,
                                   float* __restrict__ pair_w,
                                   int* __restrict__ pos_of,
                                   int* __restrict__ tiles) {
    __shared__ __align__(16) unsigned short smem[128 * 64 + 64 * 64 + 64 * 64];
    unsigned short* As  = smem;
    unsigned short* Bs1 = smem + 128 * 64;
    unsigned short* Bs3 = smem + 128 * 64 + 64 * 64;

    int bxi = blockIdx.x, byi = blockIdx.y, tid = threadIdx.x;

    if (byi == 0) {
        if (bxi) return;
        int* cnt = (int*)smem; int* seg = cnt + E_; int* cur = cnt + 2 * E_;
        if (tid < E_) { cnt[tid] = 0; cur[tid] = 0; }
        __syncthreads();
        for (int p = tid; p < NTOK * 2; p += 256) atomicAdd(&cnt[idx[p]], 1);
        __syncthreads();
        if (tid == 0) {
            int off = 0, nt = 0;
            for (int e = 0; e < E_; e++) {
                seg[e] = off;
                int te = (cnt[e] + 127) >> 7;
                for (int j = 0; j < te; j++) {
                    tiles[nt * 2] = e; tiles[nt * 2 + 1] = off + j * 128; nt++;
                }
                off += te * 128;
            }
            for (; nt < MAXTILES; nt++) { tiles[nt * 2] = -1; tiles[nt * 2 + 1] = 0; }
        }
        for (int p = tid; p < NPMAX; p += 256) pair_token[p] = -1;
        __syncthreads();
        for (int p = tid; p < NTOK * 2; p += 256) {
            int e = idx[p];
            int r = atomicAdd(&cur[e], 1);
            int pos = seg[e] + r;
            pair_token[pos] = p >> 1;
            pair_w[pos] = wts[p];
            pos_of[p] = pos;
        }
        return;
    }

    int t = byi - 1;
    if (t % 7) {
        int slot = t - t / 7 - 1;              // 0..95
        int b2 = slot * 48 + bxi;              // 0..4607
        int z = b2 / 288, r = b2 % 288;
        int by = r / 48, bx = r % 48;
        const float* s; unsigned short* d;
        if (z < 8) { s = w1 + (size_t)z * D_ * I_;       d = w1b + (size_t)z * D_ * I_; }
        else       { s = w3 + (size_t)(z - 8) * D_ * I_; d = w3b + (size_t)(z - 8) * D_ * I_; }
        transpose_tile128(s, d, D_, I_, by * 128, bx * 64, smem, tid);
        return;
    }

    int mt = t / 7;                            // 0..15
    int m0 = mt * 128;
    int n0 = bxi * 64;
    int lane = tid & 63, wave = tid >> 6;
    int wm = (wave & 1) * 64, wn = (wave >> 1) * 32;
    int l15 = lane & 15, quad = lane >> 4;

    int rl = lane >> 3, ph = lane & 7, lg = ph ^ rl;
    const unsigned short* asrc[4];
#pragma unroll
    for (int j = 0; j < 4; j++)
        asrc[j] = xb + (size_t)(m0 + j * 32 + wave * 8 + rl) * D_ + lg * 8;
    const unsigned short *b1src[2], *b3src[2];
#pragma unroll
    for (int j = 0; j < 2; j++) {
        int r = j * 32 + wave * 8 + rl;
        b1src[j] = w1sb + (size_t)(n0 + r) * D_ + lg * 8;
        b3src[j] = w3sb + (size_t)(n0 + r) * D_ + lg * 8;
    }
    unsigned short *ldA[4], *ldB1[2], *ldB3[2];
#pragma unroll
    for (int j = 0; j < 4; j++) ldA[j] = As + (j * 32 + wave * 8) * 64;
#pragma unroll
    for (int j = 0; j < 2; j++) {
        ldB1[j] = Bs1 + (j * 32 + wave * 8) * 64;
        ldB3[j] = Bs3 + (j * 32 + wave * 8) * 64;
    }

    floatx4 acc1[4][2] = {}; floatx4 acc3[4][2] = {};
    int sx = (l15 & 7);

    for (int k0 = 0; k0 < D_; k0 += 64) {
        __syncthreads();
#pragma unroll
        for (int j = 0; j < 4; j++) GLOAD_LDS16(asrc[j] + k0, ldA[j]);
#pragma unroll
        for (int j = 0; j < 2; j++) {
            GLOAD_LDS16(b1src[j] + k0, ldB1[j]);
            GLOAD_LDS16(b3src[j] + k0, ldB3[j]);
        }
        __syncthreads();

#pragma unroll
        for (int kk = 0; kk < 2; kk++) {
            int pq = ((kk * 4 + quad) ^ sx) * 8;
            bf16x8 af[4], b1f[2], b3f[2];
#pragma unroll
            for (int mi = 0; mi < 4; mi++)
                af[mi] = *(const bf16x8*)(As + (wm + mi * 16 + l15) * 64 + pq);
#pragma unroll
            for (int ni = 0; ni < 2; ni++) {
                b1f[ni] = *(const bf16x8*)(Bs1 + (wn + ni * 16 + l15) * 64 + pq);
                b3f[ni] = *(const bf16x8*)(Bs3 + (wn + ni * 16 + l15) * 64 + pq);
            }
#pragma unroll
            for (int mi = 0; mi < 4; mi++)
#pragma unroll
                for (int ni = 0; ni < 2; ni++) {
                    acc1[mi][ni] = __builtin_amdgcn_mfma_f32_16x16x32_bf16(
                        af[mi], b1f[ni], acc1[mi][ni], 0, 0, 0);
                    acc3[mi][ni] = __builtin_amdgcn_mfma_f32_16x16x32_bf16(
                        af[mi], b3f[ni], acc3[mi][ni], 0, 0, 0);
                }
        }
    }

#pragma unroll
    for (int mi = 0; mi < 4; mi++)
#pragma unroll
        for (int ni = 0; ni < 2; ni++) {
            int col = n0 + wn + ni * 16 + l15;
#pragma unroll
            for (int rr = 0; rr < 4; rr++) {
                int row = m0 + wm + mi * 16 + quad * 4 + rr;
                float g = fminf(acc1[mi][ni][rr], 10.f);
                float u = fminf(fmaxf(acc3[mi][ni][rr], -10.f), 10.f);
                float a = g / (1.f + __expf(-g)) * u;
                act[(size_t)row * I_ + col] = f2b(a);
            }
        }
}

// ------- K3: routed GEMM1 + w2 transposes + GEMM2-shared (splitk=1) ---------
// grid (48, 92): g=byi/23, h=byi%23. h<10 -> routed GEMM1 mt=g*10+h (40);
// 10<=h<22 -> w2 transpose slot g*12+(h-10) (48 rows * 48 = 2304 tiles);
// h==22 -> GEMM2-shared block id2=g*48+bxi (192 = 16 mt * 12 nx).

__launch_bounds__(256)
__global__ void gemm_routed_kernel(const unsigned short* __restrict__ xb,
                                   const unsigned short* __restrict__ w1b,
                                   const unsigned short* __restrict__ w3b,
                                   const int* __restrict__ tiles,
                                   const int* __restrict__ pair_token,
                                   unsigned short* __restrict__ act,
                                   const float* __restrict__ w2,
                                   unsigned short* __restrict__ w2b,
                                   const unsigned short* __restrict__ w2sb,
                                   float* __restrict__ outp) {
    __shared__ __align__(16) unsigned short smem[128 * 64 + 64 * 64 + 64 * 64];
    unsigned short* As  = smem;
    unsigned short* Bs1 = smem + 128 * 64;
    unsigned short* Bs3 = smem + 128 * 64 + 64 * 64;

    int bxi = blockIdx.x, byi = blockIdx.y, tid = threadIdx.x;
    int g = byi / 23, h = byi % 23;
    int lane = tid & 63, wave = tid >> 6;
    int wm = (wave & 1) * 64, wn = (wave >> 1) * 32;
    int l15 = lane & 15, quad = lane >> 4;
    int rl = lane >> 3, ph = lane & 7, lg = ph ^ rl;
    int sx = (l15 & 7);

    if (h == 22) {
        // ---- GEMM2-shared: act[0:2048) @ w2sb, full K, into outp ks0 ----
        int id2 = g * 48 + bxi;                // 0..191
        int mt2 = id2 / 12, nx = id2 % 12;
        int m0 = mt2 * 128, n0 = nx * 64;
        const unsigned short* asrc[4];
#pragma unroll
        for (int j = 0; j < 4; j++)
            asrc[j] = act + (size_t)(m0 + j * 32 + wave * 8 + rl) * I_ + lg * 8;
        const unsigned short* bsrc[2];
#pragma unroll
        for (int j = 0; j < 2; j++)
            bsrc[j] = w2sb + (size_t)(n0 + j * 32 + wave * 8 + rl) * I_ + lg * 8;
        unsigned short *ldA[4], *ldB[2];
#pragma unroll
        for (int j = 0; j < 4; j++) ldA[j] = As + (j * 32 + wave * 8) * 64;
#pragma unroll
        for (int j = 0; j < 2; j++) ldB[j] = Bs1 + (j * 32 + wave * 8) * 64;

        floatx4 acc[4][2] = {};
        for (int k0 = 0; k0 < I_; k0 += 64) {
            __syncthreads();
#pragma unroll
            for (int j = 0; j < 4; j++) GLOAD_LDS16(asrc[j] + k0, ldA[j]);
#pragma unroll
            for (int j = 0; j < 2; j++) GLOAD_LDS16(bsrc[j] + k0, ldB[j]);
            __syncthreads();
#pragma unroll
            for (int kk = 0; kk < 2; kk++) {
                int pq = ((kk * 4 + quad) ^ sx) * 8;
                bf16x8 af[4], bf[2];
#pragma unroll
                for (int mi = 0; mi < 4; mi++)
                    af[mi] = *(const bf16x8*)(As + (wm + mi * 16 + l15) * 64 + pq);
#pragma unroll
                for (int ni = 0; ni < 2; ni++)
                    bf[ni] = *(const bf16x8*)(Bs1 + (wn + ni * 16 + l15) * 64 + pq);
#pragma unroll
                for (int mi = 0; mi < 4; mi++)
#pragma unroll
                    for (int ni = 0; ni < 2; ni++)
                        acc[mi][ni] = __builtin_amdgcn_mfma_f32_16x16x32_bf16(
                            af[mi], bf[ni], acc[mi][ni], 0, 0, 0);
            }
        }
#pragma unroll
        for (int mi = 0; mi < 4; mi++)
#pragma unroll
            for (int ni = 0; ni < 2; ni++) {
                int col = n0 + wn + ni * 16 + l15;
#pragma unroll
                for (int rr = 0; rr < 4; rr++) {
                    int row = m0 + wm + mi * 16 + quad * 4 + rr;
                    outp[(size_t)row * D_ + col] = acc[mi][ni][rr];
                }
            }
        return;
    }

    if (h >= 10) {
        // ---- w2 transpose tile ----
        int slot = g * 12 + (h - 10);          // 0..47
        int b2 = slot * 48 + bxi;              // 0..2303
        int z = b2 / 288, r = b2 % 288;
        int by = r / 12, bx = r % 12;
        transpose_tile128(w2 + (size_t)z * I_ * D_, w2b + (size_t)z * I_ * D_,
                          I_, D_, by * 128, bx * 64, smem, tid);
        return;
    }

    // ---- routed GEMM1 tile ----
    int mt = g * 10 + h;                       // 0..39
    int e = tiles[mt * 2];
    if (e < 0) return;
    int m0 = NTOK + tiles[mt * 2 + 1];
    const unsigned short* B1 = w1b + (size_t)e * I_ * D_;
    const unsigned short* B3 = w3b + (size_t)e * I_ * D_;
    int n0 = bxi * 64;

    const unsigned short* asrc[4];
#pragma unroll
    for (int j = 0; j < 4; j++) {
        int r = j * 32 + wave * 8 + rl;
        int tok = pair_token[m0 - NTOK + r]; if (tok < 0) tok = 0;
        asrc[j] = xb + (size_t)tok * D_ + lg * 8;
    }
    const unsigned short *b1src[2], *b3src[2];
#pragma unroll
    for (int j = 0; j < 2; j++) {
        int r = j * 32 + wave * 8 + rl;
        b1src[j] = B1 + (size_t)(n0 + r) * D_ + lg * 8;
        b3src[j] = B3 + (size_t)(n0 + r) * D_ + lg * 8;
    }
    unsigned short *ldA[4], *ldB1[2], *ldB3[2];
#pragma unroll
    for (int j = 0; j < 4; j++) ldA[j] = As + (j * 32 + wave * 8) * 64;
#pragma unroll
    for (int j = 0; j < 2; j++) {
        ldB1[j] = Bs1 + (j * 32 + wave * 8) * 64;
        ldB3[j] = Bs3 + (j * 32 + wave * 8) * 64;
    }

    floatx4 acc1[4][2] = {}; floatx4 acc3[4][2] = {};

    for (int k0 = 0; k0 < D_; k0 += 64) {
        __syncthreads();
#pragma unroll
        for (int j = 0; j < 4; j++) GLOAD_LDS16(asrc[j] + k0, ldA[j]);
#pragma unroll
        for (int j = 0; j < 2; j++) {
            GLOAD_LDS16(b1src[j] + k0, ldB1[j]);
            GLOAD_LDS16(b3src[j] + k0, ldB3[j]);
        }
        __syncthreads();

#pragma unroll
        for (int kk = 0; kk < 2; kk++) {
            int pq = ((kk * 4 + quad) ^ sx) * 8;
            bf16x8 af[4], b1f[2], b3f[2];
#pragma unroll
            for (int mi = 0; mi < 4; mi++)
                af[mi] = *(const bf16x8*)(As + (wm + mi * 16 + l15) * 64 + pq);
#pragma unroll
            for (int ni = 0; ni < 2; ni++) {
                b1f[ni] = *(const bf16x8*)(Bs1 + (wn + ni * 16 + l15) * 64 + pq);
                b3f[ni] = *(const bf16x8*)(Bs3 + (wn + ni * 16 + l15) * 64 + pq);
            }
#pragma unroll
            for (int mi = 0; mi < 4; mi++)
#pragma unroll
                for (int ni = 0; ni < 2; ni++) {
                    acc1[mi][ni] = __builtin_amdgcn_mfma_f32_16x16x32_bf16(
                        af[mi], b1f[ni], acc1[mi][ni], 0, 0, 0);
                    acc3[mi][ni] = __builtin_amdgcn_mfma_f32_16x16x32_bf16(
                        af[mi], b3f[ni], acc3[mi][ni], 0, 0, 0);
                }
        }
    }

#pragma unroll
    for (int mi = 0; mi < 4; mi++)
#pragma unroll
        for (int ni = 0; ni < 2; ni++) {
            int col = n0 + wn + ni * 16 + l15;
#pragma unroll
            for (int rr = 0; rr < 4; rr++) {
                int row = m0 + wm + mi * 16 + quad * 4 + rr;
                float gg = fminf(acc1[mi][ni][rr], 10.f);
                float u = fminf(fmaxf(acc3[mi][ni][rr], -10.f), 10.f);
                float a = gg / (1.f + __expf(-gg)) * u;
                act[(size_t)row * I_ + col] = f2b(a);
            }
        }
}

// ---------------- K4: GEMM2-routed, split-K=2, fp32 partials ----------------

__launch_bounds__(256)
__global__ void gemm_out_kernel(const unsigned short* __restrict__ act,
                                const unsigned short* __restrict__ w2b,
                                const int* __restrict__ tiles,
                                float* __restrict__ outp) {
    __shared__ __align__(16) unsigned short As[128 * 64];
    __shared__ __align__(16) unsigned short Bs[64 * 64];

    int mt = blockIdx.y, ks = blockIdx.z;
    int kbase = ks * KS_;
    int e = tiles[mt * 2];
    if (e < 0) return;
    int m0 = NTOK + tiles[mt * 2 + 1];
    const unsigned short* B = w2b + (size_t)e * I_ * D_;
    float* C = outp + (size_t)ks * ROWS * D_;
    int n0 = blockIdx.x * 64;
    int tid = threadIdx.x;
    int lane = tid & 63, wave = tid >> 6;
    int wm = (wave & 1) * 64, wn = (wave >> 1) * 32;
    int l15 = lane & 15, quad = lane >> 4;

    int rl = lane >> 3, ph = lane & 7, lg = ph ^ rl;
    const unsigned short* asrc[4];
#pragma unroll
    for (int j = 0; j < 4; j++)
        asrc[j] = act + (size_t)(m0 + j * 32 + wave * 8 + rl) * I_ + kbase + lg * 8;
    const unsigned short* bsrc[2];
#pragma unroll
    for (int j = 0; j < 2; j++)
        bsrc[j] = B + (size_t)(n0 + j * 32 + wave * 8 + rl) * I_ + kbase + lg * 8;
    unsigned short *ldA[4], *ldB[2];
#pragma unroll
    for (int j = 0; j < 4; j++) ldA[j] = As + (j * 32 + wave * 8) * 64;
#pragma unroll
    for (int j = 0; j < 2; j++) ldB[j] = Bs + (j * 32 + wave * 8) * 64;

    floatx4 acc[4][2] = {};
    int sx = (l15 & 7);

    for (int k0 = 0; k0 < KS_; k0 += 64) {
        __syncthreads();
#pragma unroll
        for (int j = 0; j < 4; j++) GLOAD_LDS16(asrc[j] + k0, ldA[j]);
#pragma unroll
        for (int j = 0; j < 2; j++) GLOAD_LDS16(bsrc[j] + k0, ldB[j]);
        __syncthreads();

#pragma unroll
        for (int kk = 0; kk < 2; kk++) {
            int pq = ((kk * 4 + quad) ^ sx) * 8;
            bf16x8 af[4], bf[2];
#pragma unroll
            for (int mi = 0; mi < 4; mi++)
                af[mi] = *(const bf16x8*)(As + (wm + mi * 16 + l15) * 64 + pq);
#pragma unroll
            for (int ni = 0; ni < 2; ni++)
                bf[ni] = *(const bf16x8*)(Bs + (wn + ni * 16 + l15) * 64 + pq);
#pragma unroll
            for (int mi = 0; mi < 4; mi++)
#pragma unroll
                for (int ni = 0; ni < 2; ni++)
                    acc[mi][ni] = __builtin_amdgcn_mfma_f32_16x16x32_bf16(
                        af[mi], bf[ni], acc[mi][ni], 0, 0, 0);
        }
    }

#pragma unroll
    for (int mi = 0; mi < 4; mi++)
#pragma unroll
        for (int ni = 0; ni < 2; ni++) {
            int col = n0 + wn + ni * 16 + l15;
#pragma unroll
            for (int rr = 0; rr < 4; rr++) {
                int row = m0 + wm + mi * 16 + quad * 4 + rr;
                C[(size_t)row * D_ + col] = acc[mi][ni][rr];
            }
        }
}

// ---------------- K5: combine -----------------------------------------------
// shared partial: outp ks0 rows [0,2048) (full K, written by K3);
// routed partials: both ks, rows NTOK+p.

__global__ void combine_kernel(const float* __restrict__ outp,
                               const int* __restrict__ pos_of,
                               const float* __restrict__ pair_w,
                               float* __restrict__ out) {
    int gid = blockIdx.x * 256 + threadIdx.x;
    int t = gid / (D_ / 4);
    int j = (gid % (D_ / 4)) * 4;
    int p0 = pos_of[2 * t], p1 = pos_of[2 * t + 1];
    float w0 = pair_w[p0], w1 = pair_w[p1];
    const float* P0 = outp;
    const float* P1 = outp + (size_t)ROWS * D_;
    float4 a  = *(const float4*)(P0 + (size_t)t * D_ + j);
    float4 b0 = *(const float4*)(P0 + (size_t)(NTOK + p0) * D_ + j);
    float4 b1 = *(const float4*)(P1 + (size_t)(NTOK + p0) * D_ + j);
    float4 c0 = *(const float4*)(P0 + (size_t)(NTOK + p1) * D_ + j);
    float4 c1 = *(const float4*)(P1 + (size_t)(NTOK + p1) * D_ + j);
    float4 o;
    o.x = a.x + w0 * (b0.x + b1.x) + w1 * (c0.x + c1.x);
    o.y = a.y + w0 * (b0.y + b1.y) + w1 * (c0.y + c1.y);
    o.z = a.z + w0 * (b0.z + b1.z) + w1 * (c0.z + c1.z);
    o.w = a.w + w0 * (b0.w + b1.w) + w1 * (c0.w + c1.w);
    *(float4*)(out + (size_t)t * D_ + j) = o;
}

// ---------------- launch ----------------

extern "C" void kernel_launch(void* const* d_in, const int* in_sizes, int n_in,
                              void* d_out, int out_size, void* d_ws, size_t ws_size,
                              hipStream_t stream) {
    (void)in_sizes; (void)n_in; (void)out_size; (void)ws_size;
    const float* x   = (const float*)d_in[0];
    const float* gw  = (const float*)d_in[2];
    const float* gb  = (const float*)d_in[3];
    const float* w1  = (const float*)d_in[4];
    const float* w2  = (const float*)d_in[5];
    const float* w3  = (const float*)d_in[6];
    const float* w1s = (const float*)d_in[7];
    const float* w2s = (const float*)d_in[8];
    const float* w3s = (const float*)d_in[9];
    float* out = (float*)d_out;

    char* ws = (char*)d_ws;
    size_t off = 0;
    auto alloc = [&](size_t bytes) {
        size_t o = (off + 255) & ~(size_t)255;
        off = o + bytes;
        return (void*)(ws + o);
    };
    unsigned short* xb   = (unsigned short*)alloc((size_t)NTOK * D_ * 2);
    unsigned short* w1b  = (unsigned short*)alloc((size_t)E_ * I_ * D_ * 2);
    unsigned short* w3b  = (unsigned short*)alloc((size_t)E_ * I_ * D_ * 2);
    unsigned short* w2b  = (unsigned short*)alloc((size_t)E_ * I_ * D_ * 2);
    unsigned short* w1sb = (unsigned short*)alloc((size_t)I_ * D_ * 2);
    unsigned short* w3sb = (unsigned short*)alloc((size_t)I_ * D_ * 2);
    unsigned short* w2sb = (unsigned short*)alloc((size_t)I_ * D_ * 2);
    unsigned short* act  = (unsigned short*)alloc((size_t)ROWS * I_ * 2);
    float* outp = (float*)alloc((size_t)SPLITK * ROWS * D_ * 4);
    int*   idx  = (int*)alloc((size_t)NTOK * 2 * 4);
    float* wts  = (float*)alloc((size_t)NTOK * 2 * 4);
    int*   ptok = (int*)alloc((size_t)NPMAX * 4);
    float* pw   = (float*)alloc((size_t)NPMAX * 4);
    int*   posf = (int*)alloc((size_t)NTOK * 2 * 4);
    int*   tls  = (int*)alloc((size_t)MAXTILES * 2 * 4);

    prep_lite_kernel<<<2912, 256, 0, stream>>>(x, gw, gb, w1s, w3s, w2s,
                                               xb, w1sb, w3sb, w2sb, idx, wts);
    gemm_shared_kernel<<<dim3(48, 113), 256, 0, stream>>>(
        xb, w1sb, w3sb, act, w1, w3, w1b, w3b, idx, wts, ptok, pw, posf, tls);
    gemm_routed_kernel<<<dim3(48, 92), 256, 0, stream>>>(
        xb, w1b, w3b, tls, ptok, act, w2, w2b, w2sb, outp);
    gemm_out_kernel<<<dim3(D_ / 64, MAXTILES, SPLITK), 256, 0, stream>>>(
        act, w2b, tls, outp);
    combine_kernel<<<NTOK * (D_ / 4) / 256, 256, 0, stream>>>(outp, posf, pw, out);
}